// Round 1
// baseline (109.099 us; speedup 1.0000x reference)
//
#include <hip/hip_runtime.h>
#include <hip/hip_bf16.h>
#include <math.h>

#define NB 4096   // batch
#define NN 8192   // N = B * n_views
#define DD 128    // feature dim

constexpr float INV_T = 14.285714285714286f;  // 1/0.07; also the subtracted max

typedef __attribute__((ext_vector_type(8))) short bf16x8;
typedef __attribute__((ext_vector_type(4))) float f32x4;

// ---------------- kernel 1: L2-normalize rows, cast to bf16 ----------------
__global__ __launch_bounds__(256) void k_normalize(const float* __restrict__ feat,
                                                   __hip_bfloat16* __restrict__ fb) {
    int wave = (blockIdx.x * 256 + threadIdx.x) >> 6;   // one wave per row
    int lane = threadIdx.x & 63;
    const float2 v = ((const float2*)(feat + (size_t)wave * DD))[lane];
    float ss = v.x * v.x + v.y * v.y;
#pragma unroll
    for (int off = 1; off < 64; off <<= 1) ss += __shfl_xor(ss, off, 64);
    float norm  = sqrtf(ss);
    float scale = 1.0f / fmaxf(norm, 1e-12f);
    __hip_bfloat162 h2;
    h2.x = __float2bfloat16(v.x * scale);
    h2.y = __float2bfloat16(v.y * scale);
    ((__hip_bfloat162*)(fb + (size_t)wave * DD))[lane] = h2;
}

// ---------------- kernel 2: fused F*F^T + online reductions ----------------
// Wave job: 64 rows (4 tiles of 16) x 512-column j-range.
// A-frag layout (== B-frag layout for F*F^T): lane holds F[tile+(lane&15)][kt*32+(lane>>4)*8 + 0..7]
// C/D layout (m89-verified): col = lane&15, row = (lane>>4)*4 + reg.
__global__ __launch_bounds__(256) void k_main(const __hip_bfloat16* __restrict__ fbp,
                                              const int* __restrict__ labels,
                                              float* __restrict__ g_se,
                                              float* __restrict__ g_ps,
                                              float* __restrict__ g_ct) {
    const ushort* fb = (const ushort*)fbp;
    const int lane = threadIdx.x & 63;
    const int w    = threadIdx.x >> 6;
    const int job  = blockIdx.x * 4 + w;     // 0..2047
    const int rg   = job >> 4;               // 0..127 row group
    const int js   = job & 15;               // 0..15 j-split
    const int i0   = rg * 64;
    const int q    = lane >> 4;              // quad 0..3
    const int n15  = lane & 15;

    // --- load A fragments: 4 row-tiles x 4 k-tiles, resident whole kernel ---
    bf16x8 afrag[4][4];
#pragma unroll
    for (int tt = 0; tt < 4; ++tt) {
        const ushort* rp = fb + (size_t)(i0 + tt * 16 + n15) * DD + q * 8;
#pragma unroll
        for (int kt = 0; kt < 4; ++kt)
            afrag[tt][kt] = *(const bf16x8*)(rp + kt * 32);
    }

    // labels of the rows this lane accumulates (C/D row mapping)
    int labi[16];
#pragma unroll
    for (int tt = 0; tt < 4; ++tt)
#pragma unroll
        for (int r = 0; r < 4; ++r)
            labi[tt * 4 + r] = labels[(i0 + tt * 16 + q * 4 + r) & (NB - 1)];

    float a_se[16] = {};  // sum exp(l - M), j != i
    float a_ps[16] = {};  // sum over positives of (l - M)
    float a_ct[16] = {};  // positive count

    const int j0 = js * 512;
    const int jend = j0 + 512;

    // prefetch first B-fragment set
    bf16x8 bfrag[4], bnext[4];
    {
        const ushort* bp = fb + (size_t)(j0 + n15) * DD + q * 8;
#pragma unroll
        for (int kt = 0; kt < 4; ++kt) bfrag[kt] = *(const bf16x8*)(bp + kt * 32);
    }

    for (int j = j0; j < jend; j += 16) {
        // prefetch next tile's B frags (wraps harmlessly on last iter)
        int jn = (j + 16 < jend) ? (j + 16) : j0;
        const ushort* bpn = fb + (size_t)(jn + n15) * DD + q * 8;
#pragma unroll
        for (int kt = 0; kt < 4; ++kt) bnext[kt] = *(const bf16x8*)(bpn + kt * 32);

        const int jcol = j + n15;                    // this lane's output column
        const int labj = labels[jcol & (NB - 1)];

        f32x4 acc[4];
#pragma unroll
        for (int tt = 0; tt < 4; ++tt) {
            f32x4 a = {0.f, 0.f, 0.f, 0.f};
#pragma unroll
            for (int kt = 0; kt < 4; ++kt)
                a = __builtin_amdgcn_mfma_f32_16x16x32_bf16(afrag[tt][kt], bfrag[kt], a, 0, 0, 0);
            acc[tt] = a;
        }

        // epilogue: 16 (i,j) pairs per lane
#pragma unroll
        for (int tt = 0; tt < 4; ++tt) {
#pragma unroll
            for (int r = 0; r < 4; ++r) {
                const int irow = i0 + tt * 16 + q * 4 + r;
                const float l  = (acc[tt][r] - 1.0f) * INV_T;   // logit minus max
                const bool self = (irow == jcol);
                const float e = self ? 0.0f : __expf(l);
                a_se[tt * 4 + r] += e;
                const bool m = (!self) && (labi[tt * 4 + r] == labj);
                a_ps[tt * 4 + r] += m ? l : 0.0f;
                a_ct[tt * 4 + r] += m ? 1.0f : 0.0f;
            }
        }
#pragma unroll
        for (int kt = 0; kt < 4; ++kt) bfrag[kt] = bnext[kt];
    }

    // reduce the 16 lanes within each quad (they share the same rows), then atomics
#pragma unroll
    for (int s = 0; s < 16; ++s) {
        float v1 = a_se[s], v2 = a_ps[s], v3 = a_ct[s];
#pragma unroll
        for (int off = 1; off < 16; off <<= 1) {
            v1 += __shfl_xor(v1, off, 64);
            v2 += __shfl_xor(v2, off, 64);
            v3 += __shfl_xor(v3, off, 64);
        }
        if (n15 == 0) {
            const int row = i0 + (s >> 2) * 16 + q * 4 + (s & 3);
            atomicAdd(&g_se[row], v1);
            atomicAdd(&g_ps[row], v2);
            atomicAdd(&g_ct[row], v3);
        }
    }
}

// ---------------- kernel 3: per-row loss -> mean ----------------
__global__ __launch_bounds__(256) void k_final(const float* __restrict__ g_se,
                                               const float* __restrict__ g_ps,
                                               const float* __restrict__ g_ct,
                                               float* __restrict__ out) {
    int i = blockIdx.x * 256 + threadIdx.x;
    float se = g_se[i], ps = g_ps[i], c = g_ct[i];
    float lp   = ps - c * logf(se + 1e-12f);
    float loss = -lp / fmaxf(c, 1.0f);
    float v = loss * (1.0f / (float)NN);
#pragma unroll
    for (int off = 1; off < 64; off <<= 1) v += __shfl_xor(v, off, 64);
    __shared__ float sred[4];
    if ((threadIdx.x & 63) == 0) sred[threadIdx.x >> 6] = v;
    __syncthreads();
    if (threadIdx.x == 0) atomicAdd(out, sred[0] + sred[1] + sred[2] + sred[3]);
}

extern "C" void kernel_launch(void* const* d_in, const int* in_sizes, int n_in,
                              void* d_out, int out_size, void* d_ws, size_t ws_size,
                              hipStream_t stream) {
    const float* feat  = (const float*)d_in[0];
    const int* labels  = (const int*)d_in[1];
    float* out         = (float*)d_out;
    char* ws           = (char*)d_ws;

    __hip_bfloat16* fb = (__hip_bfloat16*)ws;                       // 2 MB
    float* g_se = (float*)(ws + (size_t)NN * DD * sizeof(__hip_bfloat16));
    float* g_ps = g_se + NN;
    float* g_ct = g_ps + NN;

    hipMemsetAsync(g_se, 0, 3 * NN * sizeof(float), stream);
    hipMemsetAsync(out, 0, sizeof(float), stream);

    k_normalize<<<NN / 4, 256, 0, stream>>>(feat, fb);
    k_main<<<512, 256, 0, stream>>>(fb, labels, g_se, g_ps, g_ct);
    k_final<<<NN / 256, 256, 0, stream>>>(g_se, g_ps, g_ct, out);
}